// Round 13
// baseline (88.985 us; speedup 1.0000x reference)
//
#include <hip/hip_runtime.h>

// CARAFE-style fused upsampler: B=8, C=64, H=W=128, scale=2, ks=3.
// 3-kernel pipeline:
//   K1 mean_kernel    : channel mean -> ws[0..512KB)
//   A  weights_kernel : per-px softmax weights (round-12 math; row+col
//                       validity folded post-softmax) -> ws+512KB, f32
//                       planes [b][9][256][256] (18.9MB)
//   B  carafe_stream  : pure streamer, no LDS/barriers; 36 wgt regs, 9
//                       clamped float2 tap loads + 36 FMA + 1KB/wave store
//                       per channel; batch-per-XCD (b = bid&7).
// Falls back to the round-11 fused kernel if ws_size < 19.4MB.

#define TB 256

__device__ __forceinline__ float frcp(float x) { return __builtin_amdgcn_rcpf(x); }
__device__ __forceinline__ float ftanh(float x) {
    const float e = __expf(2.0f * x);
    return 1.0f - 2.0f * frcp(e + 1.0f);
}

__global__ __launch_bounds__(256, 4) void mean_kernel(
    const float* __restrict__ x, float* __restrict__ mean)
{
    __shared__ float4 part[256];
    const int tid = threadIdx.x;
    const int bid = blockIdx.x;          // 512 blocks
    const int b   = bid >> 6;
    const int blk = bid & 63;
    const int cq  = tid >> 6;
    const int pg  = tid & 63;
    const float4* xb = (const float4*)(x + ((size_t)b * 64 + cq * 16) * 16384)
                       + blk * 64 + pg;
    float4 s = make_float4(0.f, 0.f, 0.f, 0.f);
    #pragma unroll
    for (int c = 0; c < 16; ++c) {
        float4 v = xb[(size_t)c * 4096];
        s.x += v.x; s.y += v.y; s.z += v.z; s.w += v.w;
    }
    part[tid] = s;
    __syncthreads();
    if (tid < 64) {
        float4 a = part[tid], b4 = part[64 + tid], c4 = part[128 + tid], d4 = part[192 + tid];
        float4 m = make_float4((a.x + b4.x + c4.x + d4.x) * (1.f / 64),
                               (a.y + b4.y + c4.y + d4.y) * (1.f / 64),
                               (a.z + b4.z + c4.z + d4.z) * (1.f / 64),
                               (a.w + b4.w + c4.w + d4.w) * (1.f / 64));
        ((float4*)(mean + (size_t)b * 16384))[blk * 64 + tid] = m;
    }
}

// ---------------- A: per-pixel weights ----------------
// block = (b, strip of 2 lo-res rows), 512 blocks x 256 thr (4 hi rows x 64 q)
__global__ __launch_bounds__(256, 4) void weights_kernel(
    const float* __restrict__ mean,
    const float* __restrict__ w_off,
    const float* __restrict__ b_off,
    float* __restrict__ wout)
{
    constexpr int H = 128, W = 128, HS = 256, WS = 256;
    __shared__ float ms[4][130];        // lo rows 2*s2-1 .. 2*s2+2, cols -1..128

    const int bid = blockIdx.x;
    const int b  = bid >> 6;
    const int s2 = bid & 63;
    const int tid = threadIdx.x;
    const int hy = tid >> 6;            // 0..3 hi row within strip
    const int q  = tid & 63;            // quad of hi-res cols 4q..4q+3

    const float* mb = mean + (size_t)b * (H * W);
    for (int idx = tid; idx < 520; idx += 256) {
        const int r = idx / 130, col = idx - r * 130;
        const int gy = 2 * s2 - 1 + r, gx = col - 1;
        float v = 0.f;
        if ((unsigned)gy < (unsigned)H && (unsigned)gx < (unsigned)W)
            v = mb[gy * W + gx];
        ms[r][col] = v;
    }
    __syncthreads();

    const int yr = hy >> 1;             // 0..1
    const int podd = hy & 1;
    const int Y  = 4 * s2 + hy;
    const int yc = 2 * s2 + yr;

    float m[3][4];
    #pragma unroll
    for (int r = 0; r < 3; ++r)
        #pragma unroll
        for (int cl = 0; cl < 4; ++cl)
            m[r][cl] = ms[yr + r][2 * q + cl];   // gx = 2q-1+cl

    float mrp[5][4];
    #pragma unroll
    for (int cl = 0; cl < 4; ++cl) {
        mrp[0][cl] = m[0][cl];
        mrp[1][cl] = podd ? m[1][cl] : m[0][cl];
        mrp[2][cl] = m[1][cl];
        mrp[3][cl] = podd ? m[2][cl] : m[1][cl];
        mrp[4][cl] = m[2][cl];
    }

    // column-aggregated conv coefficients (thread-uniform)
    float ce[2][5][3], co_[2][5][3];
    #pragma unroll
    for (int o = 0; o < 2; ++o)
        #pragma unroll
        for (int p = 0; p < 5; ++p) {
            const float w0 = w_off[o * 25 + p * 5 + 0];
            const float w1 = w_off[o * 25 + p * 5 + 1];
            const float w2 = w_off[o * 25 + p * 5 + 2];
            const float w3 = w_off[o * 25 + p * 5 + 3];
            const float w4 = w_off[o * 25 + p * 5 + 4];
            ce[o][p][0]  = w0 + w1;  ce[o][p][1]  = w2 + w3;  ce[o][p][2]  = w4;
            co_[o][p][0] = w0;       co_[o][p][1] = w1 + w2;  co_[o][p][2] = w3 + w4;
        }

    // validity folding (post-softmax, == reference zero-padded patches)
    const float cval0 = (q > 0) ? 1.f : 0.f;
    const float cval3 = (q < 63) ? 1.f : 0.f;
    const float cval[4] = {cval0, 1.f, 1.f, cval3};
    const float rv[3] = {(yc >= 1) ? 1.f : 0.f, 1.f, (yc <= 126) ? 1.f : 0.f};

    const float b0 = b_off[0], b1 = b_off[1];
    float wgt[4][9];
    #pragma unroll
    for (int j = 0; j < 4; ++j) {
        const int d = j >> 1;
        float o0 = 0.f, o1 = 0.f;
        if (j & 1) {
            #pragma unroll
            for (int p = 0; p < 5; ++p)
                #pragma unroll
                for (int tt = 0; tt < 3; ++tt) {
                    o0 = fmaf(co_[0][p][tt], mrp[p][d + tt], o0);
                    o1 = fmaf(co_[1][p][tt], mrp[p][d + tt], o1);
                }
        } else {
            #pragma unroll
            for (int p = 0; p < 5; ++p)
                #pragma unroll
                for (int tt = 0; tt < 3; ++tt) {
                    o0 = fmaf(ce[0][p][tt], mrp[p][d + tt], o0);
                    o1 = fmaf(ce[1][p][tt], mrp[p][d + tt], o1);
                }
        }
        const float off0 = ftanh(o0 + b0) * 0.25f;
        const float off1 = ftanh(o1 + b1) * 0.25f;
        const float s0 = (podd ? 0.25f : -0.25f) + off0;
        const float s1 = ((j & 1) ? 0.25f : -0.25f) + off1;

        const int jc = 1 + d;
        const float mctr = m[1][jc];

        float ssum = 0.f;
        float lg[9];
        #pragma unroll
        for (int k = 0; k < 9; ++k) {
            const int di = k / 3 - 1, dj = k % 3 - 1;
            const float d0 = s0 - (float)di;
            const float d1 = s1 - (float)dj;
            const float kern = frcp(fmaf(d0, d0, fmaf(d1, d1, 0.5f)));
            const float gd = m[1 + di][jc + dj] - mctr;
            const float g  = frcp(fmaf(gd, gd, 1.0f));
            lg[k] = __expf(g * kern);
            ssum += lg[k];
        }
        const float inv = frcp(ssum);
        #pragma unroll
        for (int k = 0; k < 9; ++k) {
            const int di = k / 3, dj = k % 3 - 1;   // di 0..2 row index
            wgt[j][k] = lg[k] * inv * cval[jc + dj] * rv[di];
        }
    }

    // store: planes [b][k][Y][WS], float4 per quad (coalesced 1KB/wave)
    float* wb = wout + (((size_t)b * 9) * HS + Y) * WS + 4 * q;
    #pragma unroll
    for (int k = 0; k < 9; ++k)
        *reinterpret_cast<float4*>(wb + (size_t)k * (HS * WS)) =
            make_float4(wgt[0][k], wgt[1][k], wgt[2][k], wgt[3][k]);
}

// ---------------- B: pure CARAFE streamer ----------------
// 1024 blocks: b = bid&7 (batch per XCD), band = bid>>3 (2 hi rows).
// 256 thr = chalf(2) x hy(2) x q(64). No LDS, no barriers.
__global__ __launch_bounds__(256, 4) void carafe_stream(
    const float* __restrict__ x,
    const float* __restrict__ wgtin,
    float* __restrict__ out)
{
    constexpr int H = 128, W = 128, HS = 256, WS = 256;

    const int bid = blockIdx.x;
    const int b    = bid & 7;
    const int band = bid >> 3;          // 0..127
    const int tid = threadIdx.x;
    const int chalf = tid >> 7;
    const int hy    = (tid >> 6) & 1;
    const int q     = tid & 63;
    const int Y  = band * 2 + hy;
    const int yc = band;                // = Y>>1

    // 36 weights for the 4-px quad
    float wgt[4][9];
    const float* wb = wgtin + (((size_t)b * 9) * HS + Y) * WS + 4 * q;
    #pragma unroll
    for (int k = 0; k < 9; ++k) {
        const float4 w4 = *(const float4*)(wb + (size_t)k * (HS * WS));
        wgt[0][k] = w4.x; wgt[1][k] = w4.y; wgt[2][k] = w4.z; wgt[3][k] = w4.w;
    }

    // clamped tap addressing (invalid taps have zero weight)
    int ro[3];
    ro[0] = max(yc - 1, 0) * W;
    ro[1] = yc * W;
    ro[2] = min(yc + 1, H - 1) * W;
    const int cm2 = max(2 * q - 2, 0);
    const int c00 = 2 * q;
    const int cp2 = min(2 * q + 2, W - 2);

    const float* xb = x + ((size_t)b * 64 + chalf * 32) * (H * W);
    float* ob = out + (((size_t)b * 64 + chalf * 32) * HS + Y) * WS + 4 * q;

    #pragma unroll 2
    for (int c = 0; c < 32; ++c) {
        const float* xc = xb + (size_t)c * (H * W);
        float xv[3][4];                  // xv[r][t] = x at col 2q-1+t
        #pragma unroll
        for (int r = 0; r < 3; ++r) {
            const float2 fa = *(const float2*)(xc + ro[r] + cm2);
            const float2 fb = *(const float2*)(xc + ro[r] + c00);
            const float2 fc = *(const float2*)(xc + ro[r] + cp2);
            xv[r][0] = fa.y; xv[r][1] = fb.x; xv[r][2] = fb.y; xv[r][3] = fc.x;
        }
        float a[4];
        #pragma unroll
        for (int j = 0; j < 4; ++j) {
            const int d = j >> 1;
            float acc = 0.f;
            #pragma unroll
            for (int di = 0; di < 3; ++di)
                #pragma unroll
                for (int dj = 0; dj < 3; ++dj)
                    acc = fmaf(wgt[j][di * 3 + dj], xv[di][d + dj], acc);
            a[j] = acc;
        }
        *reinterpret_cast<float4*>(ob + (size_t)c * (HS * WS)) =
            make_float4(a[0], a[1], a[2], a[3]);
    }
}

// ---------------- fallback (round-11 fused K2) ----------------
__global__ __launch_bounds__(256, 4) void carafe_main_fb(
    const float* __restrict__ x,
    const float* __restrict__ mean,
    const float* __restrict__ w_off,
    const float* __restrict__ b_off,
    float* __restrict__ out)
{
    constexpr int H = 128, W = 128, HS = 256, WS = 256;
    __shared__ float4 xs4[16][18][6];
    __shared__ float ms[18][19];
    const float2* xs2 = (const float2*)&xs4[0][0][0];

    const int tid = threadIdx.x;
    const int bid = blockIdx.x;
    const int b  = bid >> 8;
    const int t  = bid & 255;
    const int ty = t >> 5;
    const int tx = (t >> 2) & 7;
    const int cg = t & 3;
    const int y0 = ty * 16, x0 = tx * 16;
    const int c0 = cg * 16;

    const float* mb = mean + (size_t)b * (H * W);
    float mval[2];
    #pragma unroll
    for (int it = 0; it < 2; ++it) {
        const int idx = tid + it * TB;
        mval[it] = 0.f;
        if (idx < 324) {
            const int r = idx / 18, col = idx - r * 18;
            const int gy = y0 - 1 + r, gx = x0 - 1 + col;
            if ((unsigned)gy < (unsigned)H && (unsigned)gx < (unsigned)W)
                mval[it] = mb[gy * W + gx];
        }
    }
    const float* xb = x + ((size_t)b * 64 + c0) * (H * W);
    float4 pf[7];
    #pragma unroll
    for (int it = 0; it < 7; ++it) {
        const int idx = tid + it * TB;
        const int c   = idx / 108;
        const int rem = idx - c * 108;
        const int r   = rem / 6;
        const int qq  = rem - r * 6;
        const int gy  = y0 - 1 + r;
        const int cb  = x0 - 4 + 4 * qq;
        const bool v  = (idx < 1728) && ((unsigned)gy < (unsigned)H) && ((unsigned)cb < (unsigned)W);
        pf[it] = v ? *(const float4*)(xb + (c * H + gy) * W + cb)
                   : make_float4(0.f, 0.f, 0.f, 0.f);
    }
    #pragma unroll
    for (int it = 0; it < 2; ++it) {
        const int idx = tid + it * TB;
        if (idx < 324) {
            const int r = idx / 18, col = idx - r * 18;
            ms[r][col] = mval[it];
        }
    }
    __syncthreads();

    const int hy  = tid >> 3;
    const int hq  = tid & 7;
    const int yr  = hy >> 1;
    const int podd = hy & 1;
    const int Yg  = 2 * y0 + hy;
    const int Xg0 = 2 * x0 + hq * 4;

    float m[3][4];
    #pragma unroll
    for (int r = 0; r < 3; ++r)
        #pragma unroll
        for (int cl = 0; cl < 4; ++cl)
            m[r][cl] = ms[yr + r][2 * hq + cl];

    float mrp[5][4];
    #pragma unroll
    for (int cl = 0; cl < 4; ++cl) {
        mrp[0][cl] = m[0][cl];
        mrp[1][cl] = podd ? m[1][cl] : m[0][cl];
        mrp[2][cl] = m[1][cl];
        mrp[3][cl] = podd ? m[2][cl] : m[1][cl];
        mrp[4][cl] = m[2][cl];
    }
    float ce[2][5][3], co_[2][5][3];
    #pragma unroll
    for (int o = 0; o < 2; ++o)
        #pragma unroll
        for (int p = 0; p < 5; ++p) {
            const float w0 = w_off[o * 25 + p * 5 + 0];
            const float w1 = w_off[o * 25 + p * 5 + 1];
            const float w2 = w_off[o * 25 + p * 5 + 2];
            const float w3 = w_off[o * 25 + p * 5 + 3];
            const float w4 = w_off[o * 25 + p * 5 + 4];
            ce[o][p][0]  = w0 + w1;  ce[o][p][1]  = w2 + w3;  ce[o][p][2]  = w4;
            co_[o][p][0] = w0;       co_[o][p][1] = w1 + w2;  co_[o][p][2] = w3 + w4;
        }
    const float b0 = b_off[0], b1 = b_off[1];
    float wgt[4][9];
    #pragma unroll
    for (int j = 0; j < 4; ++j) {
        const int d = j >> 1;
        float o0 = 0.f, o1 = 0.f;
        if (j & 1) {
            #pragma unroll
            for (int p = 0; p < 5; ++p)
                #pragma unroll
                for (int tt = 0; tt < 3; ++tt) {
                    o0 = fmaf(co_[0][p][tt], mrp[p][d + tt], o0);
                    o1 = fmaf(co_[1][p][tt], mrp[p][d + tt], o1);
                }
        } else {
            #pragma unroll
            for (int p = 0; p < 5; ++p)
                #pragma unroll
                for (int tt = 0; tt < 3; ++tt) {
                    o0 = fmaf(ce[0][p][tt], mrp[p][d + tt], o0);
                    o1 = fmaf(ce[1][p][tt], mrp[p][d + tt], o1);
                }
        }
        const float off0 = ftanh(o0 + b0) * 0.25f;
        const float off1 = ftanh(o1 + b1) * 0.25f;
        const float s0 = (podd ? 0.25f : -0.25f) + off0;
        const float s1 = ((j & 1) ? 0.25f : -0.25f) + off1;
        const int jc = 1 + d;
        const float mctr = m[1][jc];
        float ssum = 0.f;
        float lg[9];
        #pragma unroll
        for (int k = 0; k < 9; ++k) {
            const int di = k / 3 - 1, dj = k % 3 - 1;
            const float d0 = s0 - (float)di;
            const float d1 = s1 - (float)dj;
            const float kern = frcp(fmaf(d0, d0, fmaf(d1, d1, 0.5f)));
            const float gd = m[1 + di][jc + dj] - mctr;
            const float g  = frcp(fmaf(gd, gd, 1.0f));
            lg[k] = __expf(g * kern);
            ssum += lg[k];
        }
        const float inv = frcp(ssum);
        #pragma unroll
        for (int k = 0; k < 9; ++k) wgt[j][k] = lg[k] * inv;
    }
    float4* xsl = &xs4[0][0][0];
    #pragma unroll
    for (int it = 0; it < 7; ++it) {
        const int idx = tid + it * TB;
        if (it < 6 || idx < 1728) {
            const int c   = idx / 108;
            const int rem = idx - c * 108;
            const int r   = rem / 6;
            const int qq  = rem - r * 6;
            xsl[(c * 18 + r) * 6 + qq] = pf[it];
        }
    }
    __syncthreads();

    float* ob = out + (((size_t)b * 64 + c0) * HS + Yg) * WS + Xg0;
    #pragma unroll 4
    for (int c = 0; c < 16; ++c) {
        float xv[3][4];
        #pragma unroll
        for (int r = 0; r < 3; ++r) {
            const int rb = ((c * 18) + yr + r) * 12 + hq;
            const float2 f0 = xs2[rb + 1];
            const float2 f1 = xs2[rb + 2];
            const float2 f2 = xs2[rb + 3];
            xv[r][0] = f0.y; xv[r][1] = f1.x; xv[r][2] = f1.y; xv[r][3] = f2.x;
        }
        float a[4];
        #pragma unroll
        for (int j = 0; j < 4; ++j) {
            const int px = j >> 1;
            float s = 0.f;
            #pragma unroll
            for (int di = 0; di < 3; ++di)
                #pragma unroll
                for (int dj = 0; dj < 3; ++dj)
                    s = fmaf(wgt[j][di * 3 + dj], xv[di][px + dj], s);
            a[j] = s;
        }
        *reinterpret_cast<float4*>(ob + (size_t)c * HS * WS) =
            make_float4(a[0], a[1], a[2], a[3]);
    }
}

extern "C" void kernel_launch(void* const* d_in, const int* in_sizes, int n_in,
                              void* d_out, int out_size, void* d_ws, size_t ws_size,
                              hipStream_t stream) {
    const float* x  = (const float*)d_in[0];
    const float* w  = (const float*)d_in[1];
    const float* bo = (const float*)d_in[2];
    float* out  = (float*)d_out;
    float* mean = (float*)d_ws;                        // 512 KB
    float* wgt  = (float*)d_ws + 131072;               // 18.87 MB

    const size_t need = 131072u * 4 + (size_t)8 * 9 * 65536 * 4;

    mean_kernel<<<512, TB, 0, stream>>>(x, mean);
    if (ws_size >= need) {
        weights_kernel<<<512, TB, 0, stream>>>(mean, w, bo, wgt);
        carafe_stream<<<1024, TB, 0, stream>>>(x, wgt, out);
    } else {
        carafe_main_fb<<<2048, TB, 0, stream>>>(x, mean, w, bo, out);
    }
}

// Round 15
// 43.719 us; speedup vs baseline: 2.0354x; 2.0354x over previous
//
#include <hip/hip_runtime.h>

// CARAFE-style fused upsampler: B=8, C=64, H=W=128, scale=2, ks=3.
// K1: channel mean (block-reduced, float4 coalesced) -> d_ws.
// K2: (batch, 16x16 lo-res tile, 16-ch group), 2048 blocks; fast-math weight
//     path; T14 stage split; column-aggregated conv; no-max softmax.
// Round 15: nontemporal output stores via ext_vector_type(4) (float4 /
//     HIP_vector_type is rejected by the builtin -- round-14 compile fail).

#define TB 256

typedef float floatx4 __attribute__((ext_vector_type(4)));

__device__ __forceinline__ float frcp(float x) { return __builtin_amdgcn_rcpf(x); }
__device__ __forceinline__ float ftanh(float x) {
    const float e = __expf(2.0f * x);
    return 1.0f - 2.0f * frcp(e + 1.0f);
}

__global__ __launch_bounds__(256, 4) void mean_kernel(
    const float* __restrict__ x, float* __restrict__ mean)
{
    __shared__ float4 part[256];
    const int tid = threadIdx.x;
    const int bid = blockIdx.x;          // 512 blocks: b = bid>>6, blk = bid&63
    const int b   = bid >> 6;
    const int blk = bid & 63;
    const int cq  = tid >> 6;            // 0..3
    const int pg  = tid & 63;            // 0..63
    const float4* xb = (const float4*)(x + ((size_t)b * 64 + cq * 16) * 16384)
                       + blk * 64 + pg;
    float4 s = make_float4(0.f, 0.f, 0.f, 0.f);
    #pragma unroll
    for (int c = 0; c < 16; ++c) {
        float4 v = xb[(size_t)c * 4096];
        s.x += v.x; s.y += v.y; s.z += v.z; s.w += v.w;
    }
    part[tid] = s;
    __syncthreads();
    if (tid < 64) {
        float4 a = part[tid], b4 = part[64 + tid], c4 = part[128 + tid], d4 = part[192 + tid];
        float4 m = make_float4((a.x + b4.x + c4.x + d4.x) * (1.f / 64),
                               (a.y + b4.y + c4.y + d4.y) * (1.f / 64),
                               (a.z + b4.z + c4.z + d4.z) * (1.f / 64),
                               (a.w + b4.w + c4.w + d4.w) * (1.f / 64));
        ((float4*)(mean + (size_t)b * 16384))[blk * 64 + tid] = m;
    }
}

__global__ __launch_bounds__(256, 4) void carafe_main(
    const float* __restrict__ x,
    const float* __restrict__ mean,
    const float* __restrict__ w_off,
    const float* __restrict__ b_off,
    float* __restrict__ out)
{
    constexpr int H = 128, W = 128, HS = 256, WS = 256;

    __shared__ float4 xs4[16][18][6];   // rows y0-1..y0+16, cols x0-4..x0+19
    __shared__ float ms[18][19];        // mean tile, cols x0-1..x0+16
    const float2* xs2 = (const float2*)&xs4[0][0][0];   // [16][18][12]

    const int tid = threadIdx.x;
    const int bid = blockIdx.x;
    // bid = b*256 + ty*32 + tx*4 + cg
    const int b  = bid >> 8;
    const int t  = bid & 255;
    const int ty = t >> 5;
    const int tx = (t >> 2) & 7;
    const int cg = t & 3;
    const int y0 = ty * 16, x0 = tx * 16;
    const int c0 = cg * 16;

    // ---- issue mean-tile loads (registers) ----
    const float* mb = mean + (size_t)b * (H * W);
    float mval[2];
    #pragma unroll
    for (int it = 0; it < 2; ++it) {
        const int idx = tid + it * TB;
        mval[it] = 0.f;
        if (idx < 324) {
            const int r = idx / 18, col = idx - r * 18;
            const int gy = y0 - 1 + r, gx = x0 - 1 + col;
            if ((unsigned)gy < (unsigned)H && (unsigned)gx < (unsigned)W)
                mval[it] = mb[gy * W + gx];
        }
    }

    // ---- issue x-tile loads (7 float4), written to LDS only after weights ----
    const float* xb = x + ((size_t)b * 64 + c0) * (H * W);
    float4 pf[7];
    #pragma unroll
    for (int it = 0; it < 7; ++it) {
        const int idx = tid + it * TB;
        const int c   = idx / 108;
        const int rem = idx - c * 108;
        const int r   = rem / 6;
        const int q   = rem - r * 6;
        const int gy  = y0 - 1 + r;
        const int cb  = x0 - 4 + 4 * q;
        const bool v  = (idx < 1728) && ((unsigned)gy < (unsigned)H) && ((unsigned)cb < (unsigned)W);
        pf[it] = v ? *(const float4*)(xb + (c * H + gy) * W + cb)
                   : make_float4(0.f, 0.f, 0.f, 0.f);
    }

    // ---- write + publish mean tile ----
    #pragma unroll
    for (int it = 0; it < 2; ++it) {
        const int idx = tid + it * TB;
        if (idx < 324) {
            const int r = idx / 18, col = idx - r * 18;
            ms[r][col] = mval[it];
        }
    }
    __syncthreads();

    // ---- weight math (x loads still in flight underneath) ----
    const int hy  = tid >> 3;            // 0..31 local hi-res row
    const int hq  = tid & 7;             // column group (4 px)
    const int yr  = hy >> 1;             // 0..15 local lo-res row
    const int podd = hy & 1;
    const int Yg  = 2 * y0 + hy;
    const int Xg0 = 2 * x0 + hq * 4;

    float m[3][4];
    #pragma unroll
    for (int r = 0; r < 3; ++r)
        #pragma unroll
        for (int cl = 0; cl < 4; ++cl)
            m[r][cl] = ms[yr + r][2 * hq + cl];

    // parity-resolved conv row sources (even rows {0,0,1,1,2}, odd {0,1,1,2,2})
    float mrp[5][4];
    #pragma unroll
    for (int cl = 0; cl < 4; ++cl) {
        mrp[0][cl] = m[0][cl];
        mrp[1][cl] = podd ? m[1][cl] : m[0][cl];
        mrp[2][cl] = m[1][cl];
        mrp[3][cl] = podd ? m[2][cl] : m[1][cl];
        mrp[4][cl] = m[2][cl];
    }

    // column-aggregated conv coefficients -- thread-uniform
    float ce[2][5][3], co_[2][5][3];
    #pragma unroll
    for (int o = 0; o < 2; ++o)
        #pragma unroll
        for (int p = 0; p < 5; ++p) {
            const float w0 = w_off[o * 25 + p * 5 + 0];
            const float w1 = w_off[o * 25 + p * 5 + 1];
            const float w2 = w_off[o * 25 + p * 5 + 2];
            const float w3 = w_off[o * 25 + p * 5 + 3];
            const float w4 = w_off[o * 25 + p * 5 + 4];
            ce[o][p][0]  = w0 + w1;  ce[o][p][1]  = w2 + w3;  ce[o][p][2]  = w4;
            co_[o][p][0] = w0;       co_[o][p][1] = w1 + w2;  co_[o][p][2] = w3 + w4;
        }

    const float b0 = b_off[0], b1 = b_off[1];
    float wgt[4][9];
    #pragma unroll
    for (int j = 0; j < 4; ++j) {
        const int d = j >> 1;
        float o0 = 0.f, o1 = 0.f;
        if (j & 1) {
            #pragma unroll
            for (int p = 0; p < 5; ++p)
                #pragma unroll
                for (int tt = 0; tt < 3; ++tt) {
                    o0 = fmaf(co_[0][p][tt], mrp[p][d + tt], o0);
                    o1 = fmaf(co_[1][p][tt], mrp[p][d + tt], o1);
                }
        } else {
            #pragma unroll
            for (int p = 0; p < 5; ++p)
                #pragma unroll
                for (int tt = 0; tt < 3; ++tt) {
                    o0 = fmaf(ce[0][p][tt], mrp[p][d + tt], o0);
                    o1 = fmaf(ce[1][p][tt], mrp[p][d + tt], o1);
                }
        }
        const float off0 = ftanh(o0 + b0) * 0.25f;
        const float off1 = ftanh(o1 + b1) * 0.25f;
        const float s0 = (podd ? 0.25f : -0.25f) + off0;
        const float s1 = ((j & 1) ? 0.25f : -0.25f) + off1;

        const int jc = 1 + d;
        const float mctr = m[1][jc];

        // lg = g*kern in (0,2] -> exp in (1,7.4]: no max-subtraction needed
        float ssum = 0.f;
        float lg[9];
        #pragma unroll
        for (int k = 0; k < 9; ++k) {
            const int di = k / 3 - 1, dj = k % 3 - 1;
            const float d0 = s0 - (float)di;
            const float d1 = s1 - (float)dj;
            const float kern = frcp(fmaf(d0, d0, fmaf(d1, d1, 0.5f)));
            const float gd = m[1 + di][jc + dj] - mctr;
            const float g  = frcp(fmaf(gd, gd, 1.0f));
            lg[k] = __expf(g * kern);
            ssum += lg[k];
        }
        const float inv = frcp(ssum);
        #pragma unroll
        for (int k = 0; k < 9; ++k) wgt[j][k] = lg[k] * inv;
    }

    // ---- write + publish x tile (loads have drained under weight math) ----
    float4* xsl = &xs4[0][0][0];
    #pragma unroll
    for (int it = 0; it < 7; ++it) {
        const int idx = tid + it * TB;
        if (it < 6 || idx < 1728) {
            const int c   = idx / 108;
            const int rem = idx - c * 108;
            const int r   = rem / 6;
            const int q   = rem - r * 6;
            xsl[(c * 18 + r) * 6 + q] = pf[it];
        }
    }
    __syncthreads();

    // ---- CARAFE: 16 channels; nontemporal float4 stores ----
    float* ob = out + (((size_t)b * 64 + c0) * HS + Yg) * WS + Xg0;
    #pragma unroll 4
    for (int c = 0; c < 16; ++c) {
        float xv[3][4];
        #pragma unroll
        for (int r = 0; r < 3; ++r) {
            const int rb = ((c * 18) + yr + r) * 12 + hq;   // float2 index
            const float2 f0 = xs2[rb + 1];   // cols 2hq+2, 2hq+3
            const float2 f1 = xs2[rb + 2];   // cols 2hq+4, 2hq+5
            const float2 f2 = xs2[rb + 3];   // cols 2hq+6, 2hq+7
            xv[r][0] = f0.y; xv[r][1] = f1.x; xv[r][2] = f1.y; xv[r][3] = f2.x;
        }
        float a[4];
        #pragma unroll
        for (int j = 0; j < 4; ++j) {
            const int px = j >> 1;
            float s = 0.f;
            #pragma unroll
            for (int di = 0; di < 3; ++di)
                #pragma unroll
                for (int dj = 0; dj < 3; ++dj)
                    s = fmaf(wgt[j][di * 3 + dj], xv[di][px + dj], s);
            a[j] = s;
        }
        floatx4 v4 = {a[0], a[1], a[2], a[3]};
        __builtin_nontemporal_store(v4,
            reinterpret_cast<floatx4*>(ob + (size_t)c * HS * WS));
    }
}

extern "C" void kernel_launch(void* const* d_in, const int* in_sizes, int n_in,
                              void* d_out, int out_size, void* d_ws, size_t ws_size,
                              hipStream_t stream) {
    const float* x  = (const float*)d_in[0];
    const float* w  = (const float*)d_in[1];
    const float* bo = (const float*)d_in[2];
    float* out  = (float*)d_out;
    float* mean = (float*)d_ws;            // 8*128*128 floats = 512 KB

    mean_kernel<<<512, TB, 0, stream>>>(x, mean);
    // grid: 8 batches * 8x8 tiles * 4 channel groups
    carafe_main<<<2048, TB, 0, stream>>>(x, mean, w, bo, out);
}

// Round 16
// 41.113 us; speedup vs baseline: 2.1644x; 1.0634x over previous
//
#include <hip/hip_runtime.h>

// CARAFE-style fused upsampler: B=8, C=64, H=W=128, scale=2, ks=3.
// K1: channel mean (block-reduced, float4 coalesced) -> d_ws.
// K2: (batch, 16x16 lo-res tile, 16-ch group), 2048 blocks; fast-math weight
//     path; T14 stage split; column-aggregated conv; no-max softmax;
//     NONTEMPORAL output stores (round 15: 61->44us, L2 write-pollution fix).
// Round 16: batch-per-XCD swizzle on both kernels (b = bid&7): batch j's
//     4.2MB x-slice lives in XCD j's 4MB L2; K2 halo re-reads and K1->K2
//     x re-reads become L2 hits now that NT stores stopped flushing L2.

#define TB 256

typedef float floatx4 __attribute__((ext_vector_type(4)));

__device__ __forceinline__ float frcp(float x) { return __builtin_amdgcn_rcpf(x); }
__device__ __forceinline__ float ftanh(float x) {
    const float e = __expf(2.0f * x);
    return 1.0f - 2.0f * frcp(e + 1.0f);
}

__global__ __launch_bounds__(256, 4) void mean_kernel(
    const float* __restrict__ x, float* __restrict__ mean)
{
    __shared__ float4 part[256];
    const int tid = threadIdx.x;
    const int bid = blockIdx.x;          // 512 blocks; batch-per-XCD
    const int b   = bid & 7;
    const int blk = bid >> 3;            // 0..63
    const int cq  = tid >> 6;            // 0..3
    const int pg  = tid & 63;            // 0..63
    const float4* xb = (const float4*)(x + ((size_t)b * 64 + cq * 16) * 16384)
                       + blk * 64 + pg;
    float4 s = make_float4(0.f, 0.f, 0.f, 0.f);
    #pragma unroll
    for (int c = 0; c < 16; ++c) {
        float4 v = xb[(size_t)c * 4096];
        s.x += v.x; s.y += v.y; s.z += v.z; s.w += v.w;
    }
    part[tid] = s;
    __syncthreads();
    if (tid < 64) {
        float4 a = part[tid], b4 = part[64 + tid], c4 = part[128 + tid], d4 = part[192 + tid];
        float4 m = make_float4((a.x + b4.x + c4.x + d4.x) * (1.f / 64),
                               (a.y + b4.y + c4.y + d4.y) * (1.f / 64),
                               (a.z + b4.z + c4.z + d4.z) * (1.f / 64),
                               (a.w + b4.w + c4.w + d4.w) * (1.f / 64));
        ((float4*)(mean + (size_t)b * 16384))[blk * 64 + tid] = m;
    }
}

__global__ __launch_bounds__(256, 4) void carafe_main(
    const float* __restrict__ x,
    const float* __restrict__ mean,
    const float* __restrict__ w_off,
    const float* __restrict__ b_off,
    float* __restrict__ out)
{
    constexpr int H = 128, W = 128, HS = 256, WS = 256;

    __shared__ float4 xs4[16][18][6];   // rows y0-1..y0+16, cols x0-4..x0+19
    __shared__ float ms[18][19];        // mean tile, cols x0-1..x0+16
    const float2* xs2 = (const float2*)&xs4[0][0][0];   // [16][18][12]

    const int tid = threadIdx.x;
    const int bid = blockIdx.x;
    // batch-per-XCD: b = bid&7; t = bid>>3 = ty*32 + tx*4 + cg
    const int b  = bid & 7;
    const int t  = bid >> 3;
    const int ty = t >> 5;
    const int tx = (t >> 2) & 7;
    const int cg = t & 3;
    const int y0 = ty * 16, x0 = tx * 16;
    const int c0 = cg * 16;

    // ---- issue mean-tile loads (registers) ----
    const float* mb = mean + (size_t)b * (H * W);
    float mval[2];
    #pragma unroll
    for (int it = 0; it < 2; ++it) {
        const int idx = tid + it * TB;
        mval[it] = 0.f;
        if (idx < 324) {
            const int r = idx / 18, col = idx - r * 18;
            const int gy = y0 - 1 + r, gx = x0 - 1 + col;
            if ((unsigned)gy < (unsigned)H && (unsigned)gx < (unsigned)W)
                mval[it] = mb[gy * W + gx];
        }
    }

    // ---- issue x-tile loads (7 float4), written to LDS only after weights ----
    const float* xb = x + ((size_t)b * 64 + c0) * (H * W);
    float4 pf[7];
    #pragma unroll
    for (int it = 0; it < 7; ++it) {
        const int idx = tid + it * TB;
        const int c   = idx / 108;
        const int rem = idx - c * 108;
        const int r   = rem / 6;
        const int q   = rem - r * 6;
        const int gy  = y0 - 1 + r;
        const int cb  = x0 - 4 + 4 * q;
        const bool v  = (idx < 1728) && ((unsigned)gy < (unsigned)H) && ((unsigned)cb < (unsigned)W);
        pf[it] = v ? *(const float4*)(xb + (c * H + gy) * W + cb)
                   : make_float4(0.f, 0.f, 0.f, 0.f);
    }

    // ---- write + publish mean tile ----
    #pragma unroll
    for (int it = 0; it < 2; ++it) {
        const int idx = tid + it * TB;
        if (idx < 324) {
            const int r = idx / 18, col = idx - r * 18;
            ms[r][col] = mval[it];
        }
    }
    __syncthreads();

    // ---- weight math (x loads still in flight underneath) ----
    const int hy  = tid >> 3;            // 0..31 local hi-res row
    const int hq  = tid & 7;             // column group (4 px)
    const int yr  = hy >> 1;             // 0..15 local lo-res row
    const int podd = hy & 1;
    const int Yg  = 2 * y0 + hy;
    const int Xg0 = 2 * x0 + hq * 4;

    float m[3][4];
    #pragma unroll
    for (int r = 0; r < 3; ++r)
        #pragma unroll
        for (int cl = 0; cl < 4; ++cl)
            m[r][cl] = ms[yr + r][2 * hq + cl];

    // parity-resolved conv row sources (even rows {0,0,1,1,2}, odd {0,1,1,2,2})
    float mrp[5][4];
    #pragma unroll
    for (int cl = 0; cl < 4; ++cl) {
        mrp[0][cl] = m[0][cl];
        mrp[1][cl] = podd ? m[1][cl] : m[0][cl];
        mrp[2][cl] = m[1][cl];
        mrp[3][cl] = podd ? m[2][cl] : m[1][cl];
        mrp[4][cl] = m[2][cl];
    }

    // column-aggregated conv coefficients -- thread-uniform
    float ce[2][5][3], co_[2][5][3];
    #pragma unroll
    for (int o = 0; o < 2; ++o)
        #pragma unroll
        for (int p = 0; p < 5; ++p) {
            const float w0 = w_off[o * 25 + p * 5 + 0];
            const float w1 = w_off[o * 25 + p * 5 + 1];
            const float w2 = w_off[o * 25 + p * 5 + 2];
            const float w3 = w_off[o * 25 + p * 5 + 3];
            const float w4 = w_off[o * 25 + p * 5 + 4];
            ce[o][p][0]  = w0 + w1;  ce[o][p][1]  = w2 + w3;  ce[o][p][2]  = w4;
            co_[o][p][0] = w0;       co_[o][p][1] = w1 + w2;  co_[o][p][2] = w3 + w4;
        }

    const float b0 = b_off[0], b1 = b_off[1];
    float wgt[4][9];
    #pragma unroll
    for (int j = 0; j < 4; ++j) {
        const int d = j >> 1;
        float o0 = 0.f, o1 = 0.f;
        if (j & 1) {
            #pragma unroll
            for (int p = 0; p < 5; ++p)
                #pragma unroll
                for (int tt = 0; tt < 3; ++tt) {
                    o0 = fmaf(co_[0][p][tt], mrp[p][d + tt], o0);
                    o1 = fmaf(co_[1][p][tt], mrp[p][d + tt], o1);
                }
        } else {
            #pragma unroll
            for (int p = 0; p < 5; ++p)
                #pragma unroll
                for (int tt = 0; tt < 3; ++tt) {
                    o0 = fmaf(ce[0][p][tt], mrp[p][d + tt], o0);
                    o1 = fmaf(ce[1][p][tt], mrp[p][d + tt], o1);
                }
        }
        const float off0 = ftanh(o0 + b0) * 0.25f;
        const float off1 = ftanh(o1 + b1) * 0.25f;
        const float s0 = (podd ? 0.25f : -0.25f) + off0;
        const float s1 = ((j & 1) ? 0.25f : -0.25f) + off1;

        const int jc = 1 + d;
        const float mctr = m[1][jc];

        // lg = g*kern in (0,2] -> exp in (1,7.4]: no max-subtraction needed
        float ssum = 0.f;
        float lg[9];
        #pragma unroll
        for (int k = 0; k < 9; ++k) {
            const int di = k / 3 - 1, dj = k % 3 - 1;
            const float d0 = s0 - (float)di;
            const float d1 = s1 - (float)dj;
            const float kern = frcp(fmaf(d0, d0, fmaf(d1, d1, 0.5f)));
            const float gd = m[1 + di][jc + dj] - mctr;
            const float g  = frcp(fmaf(gd, gd, 1.0f));
            lg[k] = __expf(g * kern);
            ssum += lg[k];
        }
        const float inv = frcp(ssum);
        #pragma unroll
        for (int k = 0; k < 9; ++k) wgt[j][k] = lg[k] * inv;
    }

    // ---- write + publish x tile (loads have drained under weight math) ----
    float4* xsl = &xs4[0][0][0];
    #pragma unroll
    for (int it = 0; it < 7; ++it) {
        const int idx = tid + it * TB;
        if (it < 6 || idx < 1728) {
            const int c   = idx / 108;
            const int rem = idx - c * 108;
            const int r   = rem / 6;
            const int q   = rem - r * 6;
            xsl[(c * 18 + r) * 6 + q] = pf[it];
        }
    }
    __syncthreads();

    // ---- CARAFE: 16 channels; nontemporal float4 stores ----
    float* ob = out + (((size_t)b * 64 + c0) * HS + Yg) * WS + Xg0;
    #pragma unroll 4
    for (int c = 0; c < 16; ++c) {
        float xv[3][4];
        #pragma unroll
        for (int r = 0; r < 3; ++r) {
            const int rb = ((c * 18) + yr + r) * 12 + hq;   // float2 index
            const float2 f0 = xs2[rb + 1];   // cols 2hq+2, 2hq+3
            const float2 f1 = xs2[rb + 2];   // cols 2hq+4, 2hq+5
            const float2 f2 = xs2[rb + 3];   // cols 2hq+6, 2hq+7
            xv[r][0] = f0.y; xv[r][1] = f1.x; xv[r][2] = f1.y; xv[r][3] = f2.x;
        }
        float a[4];
        #pragma unroll
        for (int j = 0; j < 4; ++j) {
            const int px = j >> 1;
            float s = 0.f;
            #pragma unroll
            for (int di = 0; di < 3; ++di)
                #pragma unroll
                for (int dj = 0; dj < 3; ++dj)
                    s = fmaf(wgt[j][di * 3 + dj], xv[di][px + dj], s);
            a[j] = s;
        }
        floatx4 v4 = {a[0], a[1], a[2], a[3]};
        __builtin_nontemporal_store(v4,
            reinterpret_cast<floatx4*>(ob + (size_t)c * HS * WS));
    }
}

extern "C" void kernel_launch(void* const* d_in, const int* in_sizes, int n_in,
                              void* d_out, int out_size, void* d_ws, size_t ws_size,
                              hipStream_t stream) {
    const float* x  = (const float*)d_in[0];
    const float* w  = (const float*)d_in[1];
    const float* bo = (const float*)d_in[2];
    float* out  = (float*)d_out;
    float* mean = (float*)d_ws;            // 8*128*128 floats = 512 KB

    mean_kernel<<<512, TB, 0, stream>>>(x, mean);
    // grid: 8 batches * 8x8 tiles * 4 channel groups (batch-per-XCD swizzle)
    carafe_main<<<2048, TB, 0, stream>>>(x, mean, w, bo, out);
}

// Round 17
// 41.108 us; speedup vs baseline: 2.1646x; 1.0001x over previous
//
#include <hip/hip_runtime.h>

// CARAFE-style fused upsampler: B=8, C=64, H=W=128, scale=2, ks=3.
// K1: channel mean (block-reduced, float4 coalesced) -> d_ws.
// K2: (batch, 16x16 lo-res tile, 16-ch group), 2048 blocks; fast-math weight
//     path; T14 stage split; column-aggregated conv; no-max softmax;
//     NONTEMPORAL output stores (r15, -28%); batch-per-XCD swizzle (r16, -6%).
// Round 17: K2 traverses tiles in REVERSE order (t = 255-t). K1 streams each
//     batch's 4.2MB x-slice through the 4MB XCD L2 in ascending rows; K2
//     ascending would always chase just-evicted lines (LRU thrash). Reversed,
//     K2's first blocks hit the rows K1 cached last.

#define TB 256

typedef float floatx4 __attribute__((ext_vector_type(4)));

__device__ __forceinline__ float frcp(float x) { return __builtin_amdgcn_rcpf(x); }
__device__ __forceinline__ float ftanh(float x) {
    const float e = __expf(2.0f * x);
    return 1.0f - 2.0f * frcp(e + 1.0f);
}

__global__ __launch_bounds__(256, 4) void mean_kernel(
    const float* __restrict__ x, float* __restrict__ mean)
{
    __shared__ float4 part[256];
    const int tid = threadIdx.x;
    const int bid = blockIdx.x;          // 512 blocks; batch-per-XCD
    const int b   = bid & 7;
    const int blk = bid >> 3;            // 0..63
    const int cq  = tid >> 6;            // 0..3
    const int pg  = tid & 63;            // 0..63
    const float4* xb = (const float4*)(x + ((size_t)b * 64 + cq * 16) * 16384)
                       + blk * 64 + pg;
    float4 s = make_float4(0.f, 0.f, 0.f, 0.f);
    #pragma unroll
    for (int c = 0; c < 16; ++c) {
        float4 v = xb[(size_t)c * 4096];
        s.x += v.x; s.y += v.y; s.z += v.z; s.w += v.w;
    }
    part[tid] = s;
    __syncthreads();
    if (tid < 64) {
        float4 a = part[tid], b4 = part[64 + tid], c4 = part[128 + tid], d4 = part[192 + tid];
        float4 m = make_float4((a.x + b4.x + c4.x + d4.x) * (1.f / 64),
                               (a.y + b4.y + c4.y + d4.y) * (1.f / 64),
                               (a.z + b4.z + c4.z + d4.z) * (1.f / 64),
                               (a.w + b4.w + c4.w + d4.w) * (1.f / 64));
        ((float4*)(mean + (size_t)b * 16384))[blk * 64 + tid] = m;
    }
}

__global__ __launch_bounds__(256, 4) void carafe_main(
    const float* __restrict__ x,
    const float* __restrict__ mean,
    const float* __restrict__ w_off,
    const float* __restrict__ b_off,
    float* __restrict__ out)
{
    constexpr int H = 128, W = 128, HS = 256, WS = 256;

    __shared__ float4 xs4[16][18][6];   // rows y0-1..y0+16, cols x0-4..x0+19
    __shared__ float ms[18][19];        // mean tile, cols x0-1..x0+16
    const float2* xs2 = (const float2*)&xs4[0][0][0];   // [16][18][12]

    const int tid = threadIdx.x;
    const int bid = blockIdx.x;
    // batch-per-XCD: b = bid&7; reversed tile order (anti-LRU vs K1's stream)
    const int b  = bid & 7;
    const int t  = 255 - (bid >> 3);
    const int ty = t >> 5;
    const int tx = (t >> 2) & 7;
    const int cg = t & 3;
    const int y0 = ty * 16, x0 = tx * 16;
    const int c0 = cg * 16;

    // ---- issue mean-tile loads (registers) ----
    const float* mb = mean + (size_t)b * (H * W);
    float mval[2];
    #pragma unroll
    for (int it = 0; it < 2; ++it) {
        const int idx = tid + it * TB;
        mval[it] = 0.f;
        if (idx < 324) {
            const int r = idx / 18, col = idx - r * 18;
            const int gy = y0 - 1 + r, gx = x0 - 1 + col;
            if ((unsigned)gy < (unsigned)H && (unsigned)gx < (unsigned)W)
                mval[it] = mb[gy * W + gx];
        }
    }

    // ---- issue x-tile loads (7 float4), written to LDS only after weights ----
    const float* xb = x + ((size_t)b * 64 + c0) * (H * W);
    float4 pf[7];
    #pragma unroll
    for (int it = 0; it < 7; ++it) {
        const int idx = tid + it * TB;
        const int c   = idx / 108;
        const int rem = idx - c * 108;
        const int r   = rem / 6;
        const int q   = rem - r * 6;
        const int gy  = y0 - 1 + r;
        const int cb  = x0 - 4 + 4 * q;
        const bool v  = (idx < 1728) && ((unsigned)gy < (unsigned)H) && ((unsigned)cb < (unsigned)W);
        pf[it] = v ? *(const float4*)(xb + (c * H + gy) * W + cb)
                   : make_float4(0.f, 0.f, 0.f, 0.f);
    }

    // ---- write + publish mean tile ----
    #pragma unroll
    for (int it = 0; it < 2; ++it) {
        const int idx = tid + it * TB;
        if (idx < 324) {
            const int r = idx / 18, col = idx - r * 18;
            ms[r][col] = mval[it];
        }
    }
    __syncthreads();

    // ---- weight math (x loads still in flight underneath) ----
    const int hy  = tid >> 3;            // 0..31 local hi-res row
    const int hq  = tid & 7;             // column group (4 px)
    const int yr  = hy >> 1;             // 0..15 local lo-res row
    const int podd = hy & 1;
    const int Yg  = 2 * y0 + hy;
    const int Xg0 = 2 * x0 + hq * 4;

    float m[3][4];
    #pragma unroll
    for (int r = 0; r < 3; ++r)
        #pragma unroll
        for (int cl = 0; cl < 4; ++cl)
            m[r][cl] = ms[yr + r][2 * hq + cl];

    // parity-resolved conv row sources (even rows {0,0,1,1,2}, odd {0,1,1,2,2})
    float mrp[5][4];
    #pragma unroll
    for (int cl = 0; cl < 4; ++cl) {
        mrp[0][cl] = m[0][cl];
        mrp[1][cl] = podd ? m[1][cl] : m[0][cl];
        mrp[2][cl] = m[1][cl];
        mrp[3][cl] = podd ? m[2][cl] : m[1][cl];
        mrp[4][cl] = m[2][cl];
    }

    // column-aggregated conv coefficients -- thread-uniform
    float ce[2][5][3], co_[2][5][3];
    #pragma unroll
    for (int o = 0; o < 2; ++o)
        #pragma unroll
        for (int p = 0; p < 5; ++p) {
            const float w0 = w_off[o * 25 + p * 5 + 0];
            const float w1 = w_off[o * 25 + p * 5 + 1];
            const float w2 = w_off[o * 25 + p * 5 + 2];
            const float w3 = w_off[o * 25 + p * 5 + 3];
            const float w4 = w_off[o * 25 + p * 5 + 4];
            ce[o][p][0]  = w0 + w1;  ce[o][p][1]  = w2 + w3;  ce[o][p][2]  = w4;
            co_[o][p][0] = w0;       co_[o][p][1] = w1 + w2;  co_[o][p][2] = w3 + w4;
        }

    const float b0 = b_off[0], b1 = b_off[1];
    float wgt[4][9];
    #pragma unroll
    for (int j = 0; j < 4; ++j) {
        const int d = j >> 1;
        float o0 = 0.f, o1 = 0.f;
        if (j & 1) {
            #pragma unroll
            for (int p = 0; p < 5; ++p)
                #pragma unroll
                for (int tt = 0; tt < 3; ++tt) {
                    o0 = fmaf(co_[0][p][tt], mrp[p][d + tt], o0);
                    o1 = fmaf(co_[1][p][tt], mrp[p][d + tt], o1);
                }
        } else {
            #pragma unroll
            for (int p = 0; p < 5; ++p)
                #pragma unroll
                for (int tt = 0; tt < 3; ++tt) {
                    o0 = fmaf(ce[0][p][tt], mrp[p][d + tt], o0);
                    o1 = fmaf(ce[1][p][tt], mrp[p][d + tt], o1);
                }
        }
        const float off0 = ftanh(o0 + b0) * 0.25f;
        const float off1 = ftanh(o1 + b1) * 0.25f;
        const float s0 = (podd ? 0.25f : -0.25f) + off0;
        const float s1 = ((j & 1) ? 0.25f : -0.25f) + off1;

        const int jc = 1 + d;
        const float mctr = m[1][jc];

        // lg = g*kern in (0,2] -> exp in (1,7.4]: no max-subtraction needed
        float ssum = 0.f;
        float lg[9];
        #pragma unroll
        for (int k = 0; k < 9; ++k) {
            const int di = k / 3 - 1, dj = k % 3 - 1;
            const float d0 = s0 - (float)di;
            const float d1 = s1 - (float)dj;
            const float kern = frcp(fmaf(d0, d0, fmaf(d1, d1, 0.5f)));
            const float gd = m[1 + di][jc + dj] - mctr;
            const float g  = frcp(fmaf(gd, gd, 1.0f));
            lg[k] = __expf(g * kern);
            ssum += lg[k];
        }
        const float inv = frcp(ssum);
        #pragma unroll
        for (int k = 0; k < 9; ++k) wgt[j][k] = lg[k] * inv;
    }

    // ---- write + publish x tile (loads have drained under weight math) ----
    float4* xsl = &xs4[0][0][0];
    #pragma unroll
    for (int it = 0; it < 7; ++it) {
        const int idx = tid + it * TB;
        if (it < 6 || idx < 1728) {
            const int c   = idx / 108;
            const int rem = idx - c * 108;
            const int r   = rem / 6;
            const int q   = rem - r * 6;
            xsl[(c * 18 + r) * 6 + q] = pf[it];
        }
    }
    __syncthreads();

    // ---- CARAFE: 16 channels; nontemporal float4 stores ----
    float* ob = out + (((size_t)b * 64 + c0) * HS + Yg) * WS + Xg0;
    #pragma unroll 4
    for (int c = 0; c < 16; ++c) {
        float xv[3][4];
        #pragma unroll
        for (int r = 0; r < 3; ++r) {
            const int rb = ((c * 18) + yr + r) * 12 + hq;   // float2 index
            const float2 f0 = xs2[rb + 1];   // cols 2hq+2, 2hq+3
            const float2 f1 = xs2[rb + 2];   // cols 2hq+4, 2hq+5
            const float2 f2 = xs2[rb + 3];   // cols 2hq+6, 2hq+7
            xv[r][0] = f0.y; xv[r][1] = f1.x; xv[r][2] = f1.y; xv[r][3] = f2.x;
        }
        float a[4];
        #pragma unroll
        for (int j = 0; j < 4; ++j) {
            const int px = j >> 1;
            float s = 0.f;
            #pragma unroll
            for (int di = 0; di < 3; ++di)
                #pragma unroll
                for (int dj = 0; dj < 3; ++dj)
                    s = fmaf(wgt[j][di * 3 + dj], xv[di][px + dj], s);
            a[j] = s;
        }
        floatx4 v4 = {a[0], a[1], a[2], a[3]};
        __builtin_nontemporal_store(v4,
            reinterpret_cast<floatx4*>(ob + (size_t)c * HS * WS));
    }
}

extern "C" void kernel_launch(void* const* d_in, const int* in_sizes, int n_in,
                              void* d_out, int out_size, void* d_ws, size_t ws_size,
                              hipStream_t stream) {
    const float* x  = (const float*)d_in[0];
    const float* w  = (const float*)d_in[1];
    const float* bo = (const float*)d_in[2];
    float* out  = (float*)d_out;
    float* mean = (float*)d_ws;            // 8*128*128 floats = 512 KB

    mean_kernel<<<512, TB, 0, stream>>>(x, mean);
    // grid: 8 batches * 8x8 tiles * 4 channel groups (batch-per-XCD, reversed)
    carafe_main<<<2048, TB, 0, stream>>>(x, mean, w, bo, out);
}